// Round 1
// baseline (809.044 us; speedup 1.0000x reference)
//
#include <hip/hip_runtime.h>

#define NP 25088   // B * oH * oW = 8*56*56
#define DD 576     // 64 * 3 * 3
#define KC 256     // centroids

// ---------------- unfold: x[8,64,56,56] -> P^T[576][25088], d = c*9+i*3+j ----
__global__ __launch_bounds__(256) void unfold_kernel(const float* __restrict__ x,
                                                     float* __restrict__ PT) {
  const int d = blockIdx.y;                       // 0..575
  const int n = blockIdx.x * 256 + threadIdx.x;   // 0..25087
  const int c = d / 9, r = d % 9;
  const int di = r / 3 - 1, dj = r % 3 - 1;
  const int b = n / 3136, hw = n % 3136;
  const int h = hw / 56 + di, w = hw % 56 + dj;
  float v = 0.0f;
  if (h >= 0 && h < 56 && w >= 0 && w < 56)
    v = x[(((size_t)b * 64 + c) * 56 + h) * 56 + w];
  PT[(size_t)d * NP + n] = v;
}

// ---------------- centroid transpose: C[256][576] -> C^T[576][256] -----------
__global__ __launch_bounds__(256) void transpose_kernel(const float* __restrict__ C,
                                                        float* __restrict__ CT) {
  const int d = blockIdx.x;      // 576
  const int k = threadIdx.x;     // 256
  CT[d * KC + k] = C[k * DD + d];
}

// ---------------- nearest: argmin_k sum_d |A^T[d][m] - C^T[d][k]| ------------
// block: 64 patches x 256 centroids (2 k-chunks of 128). 256 threads.
// thread tile 4m x 8k. Dc=32, double-buffered LDS, split accumulation
// (part over 64-d segments -> tot) for summation accuracy (argmin tie safety).
__global__ __launch_bounds__(256) void nearest_kernel(const float* __restrict__ AT,
                                                      const float* __restrict__ CT,
                                                      int* __restrict__ idx_out) {
  __shared__ float As[2][32][64];    // [buf][d][m]   16 KB
  __shared__ float Bs[2][32][128];   // [buf][d][k]   32 KB

  const int tid = threadIdx.x;
  const int tm = tid >> 4;           // 0..15 -> m = tm*4 + i
  const int tk = tid & 15;           // 0..15 -> k = {tk*4+j, 64+tk*4+j}
  const int m0 = blockIdx.x * 64;

  float part[4][8], tot[4][8];
  float rbest[4];
  int rbidx[4];
  float4 ra[2], rb[4];

#define LOADT(ch, kc) do {                                                          \
    _Pragma("unroll")                                                               \
    for (int q = 0; q < 2; ++q) {                                                   \
      int f = q * 256 + tid;                                                        \
      ra[q] = *(const float4*)(AT + (size_t)((ch) * 32 + (f >> 4)) * NP + m0 +      \
                               (f & 15) * 4);                                       \
    }                                                                               \
    _Pragma("unroll")                                                               \
    for (int q = 0; q < 4; ++q) {                                                   \
      int f = q * 256 + tid;                                                        \
      rb[q] = *(const float4*)(CT + (size_t)((ch) * 32 + (f >> 5)) * KC +           \
                               (kc) * 128 + (f & 31) * 4);                          \
    }                                                                               \
  } while (0)

#define WRITET(bf) do {                                                             \
    _Pragma("unroll")                                                               \
    for (int q = 0; q < 2; ++q) {                                                   \
      int f = q * 256 + tid;                                                        \
      *(float4*)&As[bf][f >> 4][(f & 15) * 4] = ra[q];                              \
    }                                                                               \
    _Pragma("unroll")                                                               \
    for (int q = 0; q < 4; ++q) {                                                   \
      int f = q * 256 + tid;                                                        \
      *(float4*)&Bs[bf][f >> 5][(f & 31) * 4] = rb[q];                              \
    }                                                                               \
  } while (0)

  for (int kc = 0; kc < 2; ++kc) {
    LOADT(0, kc);
    WRITET(0);
#pragma unroll
    for (int i = 0; i < 4; ++i)
#pragma unroll
      for (int j = 0; j < 8; ++j) tot[i][j] = 0.0f;

    for (int ch = 0; ch < 18; ++ch) {            // 18 * 32 = 576 d's
      if ((ch & 1) == 0) {
#pragma unroll
        for (int i = 0; i < 4; ++i)
#pragma unroll
          for (int j = 0; j < 8; ++j) part[i][j] = 0.0f;
      }
      __syncthreads();                           // staged buf (ch&1) visible
      if (ch < 17) LOADT(ch + 1, kc);            // issue next-chunk global loads
      const int buf = ch & 1;
#pragma unroll 4
      for (int d = 0; d < 32; ++d) {
        float a[4], b[8];
        *(float4*)&a[0] = *(const float4*)&As[buf][d][tm * 4];
        *(float4*)&b[0] = *(const float4*)&Bs[buf][d][tk * 4];
        *(float4*)&b[4] = *(const float4*)&Bs[buf][d][64 + tk * 4];
#pragma unroll
        for (int i = 0; i < 4; ++i)
#pragma unroll
          for (int j = 0; j < 8; ++j) part[i][j] += fabsf(a[i] - b[j]);
      }
      if (ch < 17) WRITET((ch + 1) & 1);         // ds_write after compute (T14)
      if (ch & 1) {                               // segment flush (64 d's)
#pragma unroll
        for (int i = 0; i < 4; ++i)
#pragma unroll
          for (int j = 0; j < 8; ++j) tot[i][j] += part[i][j];
      }
    }

    // per-thread argmin over its 8 k's (ascending k, strict < => first-min),
    // then butterfly reduce across the 16 tk lanes sharing this m-row.
#pragma unroll
    for (int i = 0; i < 4; ++i) {
      float bd = tot[i][0];
      int bk = kc * 128 + tk * 4;
#pragma unroll
      for (int j = 1; j < 8; ++j) {
        int kk = kc * 128 + (j < 4 ? tk * 4 + j : 64 + tk * 4 + (j - 4));
        if (tot[i][j] < bd) { bd = tot[i][j]; bk = kk; }
      }
#pragma unroll
      for (int off = 1; off < 16; off <<= 1) {
        float od = __shfl_xor(bd, off, 64);
        int ok = __shfl_xor(bk, off, 64);
        if (od < bd || (od == bd && ok < bk)) { bd = od; bk = ok; }
      }
      if (kc == 0) { rbest[i] = bd; rbidx[i] = bk; }
      else if (bd < rbest[i]) { rbest[i] = bd; rbidx[i] = bk; }  // tie keeps kc0
    }
  }

  if (tk == 0) {
#pragma unroll
    for (int i = 0; i < 4; ++i) idx_out[m0 + tm * 4 + i] = rbidx[i];
  }
#undef LOADT
#undef WRITET
}

// ---------------- residual in place: P^T[d][n] -= C1^T[d][idx1[n]] -----------
__global__ __launch_bounds__(256) void resid_kernel(float* __restrict__ PT,
                                                    const float* __restrict__ C1T,
                                                    const int* __restrict__ idx1) {
  const int d = blockIdx.y;
  const int n = blockIdx.x * 256 + threadIdx.x;
  const int k = idx1[n];
  PT[(size_t)d * NP + n] -= C1T[d * KC + k];
}

// ---------------- BN stats: per-channel sum & sumsq of LUT outputs -----------
__global__ __launch_bounds__(256) void stats_kernel(const int* __restrict__ idx1,
                                                    const int* __restrict__ idx2,
                                                    const float* __restrict__ dotc,
                                                    const float* __restrict__ dotrc,
                                                    float* __restrict__ gsum,
                                                    float* __restrict__ gsq) {
  __shared__ float ssum[4][128], ssq[4][128];
  const int tid = threadIdx.x, lane = tid & 63, wv = tid >> 6;
  const int wid = blockIdx.x * 4 + wv;           // 0..511
  float s0 = 0.f, s1 = 0.f, q0 = 0.f, q1 = 0.f;
  for (int n = wid; n < NP; n += 512) {          // 25088 = 512*49
    const int k1 = idx1[n], k2 = idx2[n];
    const float2 u = ((const float2*)(dotc + (size_t)k1 * 128))[lane];
    const float2 v = ((const float2*)(dotrc + (size_t)k2 * 128))[lane];
    const float x0 = u.x + v.x, x1 = u.y + v.y;
    s0 += x0; s1 += x1; q0 += x0 * x0; q1 += x1 * x1;
  }
  ssum[wv][lane * 2] = s0; ssum[wv][lane * 2 + 1] = s1;
  ssq[wv][lane * 2] = q0;  ssq[wv][lane * 2 + 1] = q1;
  __syncthreads();
  if (tid < 128) {
    const float s = ssum[0][tid] + ssum[1][tid] + ssum[2][tid] + ssum[3][tid];
    const float q = ssq[0][tid] + ssq[1][tid] + ssq[2][tid] + ssq[3][tid];
    atomicAdd(&gsum[tid], s);
    atomicAdd(&gsq[tid], q);
  }
}

__global__ void finalize_kernel(const float* __restrict__ gsum,
                                const float* __restrict__ gsq,
                                const float* __restrict__ gamma,
                                const float* __restrict__ beta,
                                float* __restrict__ scalev,
                                float* __restrict__ shiftv) {
  const int c = threadIdx.x;                     // 128
  const float mean = gsum[c] * (1.0f / NP);
  const float var = gsq[c] * (1.0f / NP) - mean * mean;
  const float inv = rsqrtf(var + 1e-5f);
  const float sc = gamma[c] * inv;
  scalev[c] = sc;
  shiftv[c] = beta[c] - mean * sc;
}

// ---------------- output: LUT gather + affine BN + [B,C,H,W] store -----------
__global__ __launch_bounds__(256) void output_kernel(const int* __restrict__ idx1,
                                                     const int* __restrict__ idx2,
                                                     const float* __restrict__ dotc,
                                                     const float* __restrict__ dotrc,
                                                     const float* __restrict__ scalev,
                                                     const float* __restrict__ shiftv,
                                                     float* __restrict__ out) {
  __shared__ float vals[64][128];                // [n-local][c]  32 KB
  const int tid = threadIdx.x, lane = tid & 63, wv = tid >> 6;
  const int blk = blockIdx.x;                    // 392 = 8 * 49
  const int b = blk / 49, hw0 = (blk % 49) * 64;
  const int n0 = b * 3136 + hw0;
  const float sc0 = scalev[lane * 2], sc1 = scalev[lane * 2 + 1];
  const float sh0 = shiftv[lane * 2], sh1 = shiftv[lane * 2 + 1];
  for (int t = 0; t < 16; ++t) {
    const int nn = wv * 16 + t;
    const int n = n0 + nn;
    const int k1 = idx1[n], k2 = idx2[n];
    const float2 u = ((const float2*)(dotc + (size_t)k1 * 128))[lane];
    const float2 v = ((const float2*)(dotrc + (size_t)k2 * 128))[lane];
    *(float2*)&vals[nn][lane * 2] =
        make_float2(sc0 * (u.x + v.x) + sh0, sc1 * (u.y + v.y) + sh1);
  }
  __syncthreads();
  const int c = tid >> 1, half = tid & 1;
  float* op = out + ((size_t)b * 128 + c) * 3136 + hw0 + half * 32;
#pragma unroll
  for (int i = 0; i < 32; i += 4) {
    float4 w4;
    w4.x = vals[half * 32 + i + 0][c];
    w4.y = vals[half * 32 + i + 1][c];
    w4.z = vals[half * 32 + i + 2][c];
    w4.w = vals[half * 32 + i + 3][c];
    *(float4*)(op + i) = w4;
  }
}

extern "C" void kernel_launch(void* const* d_in, const int* in_sizes, int n_in,
                              void* d_out, int out_size, void* d_ws, size_t ws_size,
                              hipStream_t stream) {
  const float* x     = (const float*)d_in[0];
  const float* cent  = (const float*)d_in[1];
  const float* rcent = (const float*)d_in[2];
  const float* dotc  = (const float*)d_in[3];
  const float* dotrc = (const float*)d_in[4];
  const float* gamma = (const float*)d_in[5];
  const float* beta  = (const float*)d_in[6];
  float* out = (float*)d_out;

  // workspace layout (~59.3 MB)
  float* PT  = (float*)d_ws;                 // [576][25088]
  float* C1T = PT + (size_t)DD * NP;         // [576][256]
  float* C2T = C1T + (size_t)DD * KC;        // [576][256]
  int* idx1  = (int*)(C2T + (size_t)DD * KC);
  int* idx2  = idx1 + NP;
  float* gsum   = (float*)(idx2 + NP);       // [128]
  float* gsq    = gsum + 128;                // [128]
  float* scalev = gsq + 128;                 // [128]
  float* shiftv = scalev + 128;              // [128]

  unfold_kernel<<<dim3(98, 576), 256, 0, stream>>>(x, PT);
  transpose_kernel<<<576, 256, 0, stream>>>(cent, C1T);
  transpose_kernel<<<576, 256, 0, stream>>>(rcent, C2T);
  nearest_kernel<<<392, 256, 0, stream>>>(PT, C1T, idx1);
  resid_kernel<<<dim3(98, 576), 256, 0, stream>>>(PT, C1T, idx1);
  nearest_kernel<<<392, 256, 0, stream>>>(PT, C2T, idx2);
  hipMemsetAsync(gsum, 0, 256 * sizeof(float), stream);
  stats_kernel<<<128, 256, 0, stream>>>(idx1, idx2, dotc, dotrc, gsum, gsq);
  finalize_kernel<<<1, 128, 0, stream>>>(gsum, gsq, gamma, beta, scalev, shiftv);
  output_kernel<<<392, 256, 0, stream>>>(idx1, idx2, dotc, dotrc, scalev, shiftv, out);
}

// Round 2
// 745.934 us; speedup vs baseline: 1.0846x; 1.0846x over previous
//
#include <hip/hip_runtime.h>

#define NP 25088   // B * oH * oW = 8*56*56
#define DD 576     // 64 * 3 * 3
#define KC 256     // centroids

// ---------------- unfold: x[8,64,56,56] -> P^T[576][25088], d = c*9+i*3+j ----
__global__ __launch_bounds__(256) void unfold_kernel(const float* __restrict__ x,
                                                     float* __restrict__ PT) {
  const int d = blockIdx.y;                       // 0..575
  const int n = blockIdx.x * 256 + threadIdx.x;   // 0..25087
  const int c = d / 9, r = d % 9;
  const int di = r / 3 - 1, dj = r % 3 - 1;
  const int b = n / 3136, hw = n % 3136;
  const int h = hw / 56 + di, w = hw % 56 + dj;
  float v = 0.0f;
  if (h >= 0 && h < 56 && w >= 0 && w < 56)
    v = x[(((size_t)b * 64 + c) * 56 + h) * 56 + w];
  PT[(size_t)d * NP + n] = v;
}

// ---------------- centroid transpose: C[256][576] -> C^T[576][256] -----------
__global__ __launch_bounds__(256) void transpose_kernel(const float* __restrict__ C,
                                                        float* __restrict__ CT) {
  const int d = blockIdx.x;      // 576
  const int k = threadIdx.x;     // 256
  CT[d * KC + k] = C[k * DD + d];
}

// ---------------- nearest: per-block best over a 128-k slab ------------------
// block: 64 patches x 128 centroids (kc = blockIdx.y selects slab).
// grid (392, 2) = 784 blocks -> ~3 blocks/CU resident (48 KB LDS).
// 256 threads, thread tile 4m x 8k. Dc=32 double-buffered LDS, split
// accumulation (64-d segments) for summation accuracy (argmin tie safety).
__global__ __launch_bounds__(256) void nearest_kernel(const float* __restrict__ AT,
                                                      const float* __restrict__ CT,
                                                      float* __restrict__ distc,
                                                      int* __restrict__ idxc) {
  __shared__ float As[2][32][64];    // [buf][d][m]   16 KB
  __shared__ float Bs[2][32][128];   // [buf][d][k]   32 KB

  const int tid = threadIdx.x;
  const int tm = tid >> 4;           // 0..15 -> m = tm*4 + i
  const int tk = tid & 15;           // 0..15 -> k = kc*128 + {tk*4+j, 64+tk*4+j}
  const int m0 = blockIdx.x * 64;
  const int kc = blockIdx.y;

  float part[4][8], tot[4][8];
  float4 ra[2], rb[4];

#define LOADT(ch) do {                                                              \
    _Pragma("unroll")                                                               \
    for (int q = 0; q < 2; ++q) {                                                   \
      int f = q * 256 + tid;                                                        \
      ra[q] = *(const float4*)(AT + (size_t)((ch) * 32 + (f >> 4)) * NP + m0 +      \
                               (f & 15) * 4);                                       \
    }                                                                               \
    _Pragma("unroll")                                                               \
    for (int q = 0; q < 4; ++q) {                                                   \
      int f = q * 256 + tid;                                                        \
      rb[q] = *(const float4*)(CT + (size_t)((ch) * 32 + (f >> 5)) * KC +           \
                               kc * 128 + (f & 31) * 4);                            \
    }                                                                               \
  } while (0)

#define WRITET(bf) do {                                                             \
    _Pragma("unroll")                                                               \
    for (int q = 0; q < 2; ++q) {                                                   \
      int f = q * 256 + tid;                                                        \
      *(float4*)&As[bf][f >> 4][(f & 15) * 4] = ra[q];                              \
    }                                                                               \
    _Pragma("unroll")                                                               \
    for (int q = 0; q < 4; ++q) {                                                   \
      int f = q * 256 + tid;                                                        \
      *(float4*)&Bs[bf][f >> 5][(f & 31) * 4] = rb[q];                              \
    }                                                                               \
  } while (0)

  LOADT(0);
  WRITET(0);
#pragma unroll
  for (int i = 0; i < 4; ++i)
#pragma unroll
    for (int j = 0; j < 8; ++j) tot[i][j] = 0.0f;

  for (int ch = 0; ch < 18; ++ch) {            // 18 * 32 = 576 d's
    if ((ch & 1) == 0) {
#pragma unroll
      for (int i = 0; i < 4; ++i)
#pragma unroll
        for (int j = 0; j < 8; ++j) part[i][j] = 0.0f;
    }
    __syncthreads();                           // staged buf (ch&1) visible
    if (ch < 17) LOADT(ch + 1);                // issue next-chunk global loads
    const int buf = ch & 1;
#pragma unroll 4
    for (int d = 0; d < 32; ++d) {
      float a[4], b[8];
      *(float4*)&a[0] = *(const float4*)&As[buf][d][tm * 4];
      *(float4*)&b[0] = *(const float4*)&Bs[buf][d][tk * 4];
      *(float4*)&b[4] = *(const float4*)&Bs[buf][d][64 + tk * 4];
#pragma unroll
      for (int i = 0; i < 4; ++i)
#pragma unroll
        for (int j = 0; j < 8; ++j) part[i][j] += fabsf(a[i] - b[j]);
    }
    if (ch < 17) WRITET((ch + 1) & 1);         // ds_write after compute (T14)
    if (ch & 1) {                              // segment flush (64 d's)
#pragma unroll
      for (int i = 0; i < 4; ++i)
#pragma unroll
        for (int j = 0; j < 8; ++j) tot[i][j] += part[i][j];
    }
  }

  // per-thread argmin over its 8 k's (ascending k, strict < => first-min),
  // then butterfly reduce across the 16 tk lanes sharing this m-row.
#pragma unroll
  for (int i = 0; i < 4; ++i) {
    float bd = tot[i][0];
    int bk = kc * 128 + tk * 4;
#pragma unroll
    for (int j = 1; j < 8; ++j) {
      int kk = kc * 128 + (j < 4 ? tk * 4 + j : 64 + tk * 4 + (j - 4));
      if (tot[i][j] < bd) { bd = tot[i][j]; bk = kk; }
    }
#pragma unroll
    for (int off = 1; off < 16; off <<= 1) {
      float od = __shfl_xor(bd, off, 64);
      int ok = __shfl_xor(bk, off, 64);
      if (od < bd || (od == bd && ok < bk)) { bd = od; bk = ok; }
    }
    if (tk == 0) {
      const int m = m0 + tm * 4 + i;
      distc[(size_t)kc * NP + m] = bd;
      idxc[(size_t)kc * NP + m] = bk;
    }
  }
#undef LOADT
#undef WRITET
}

// ---------------- combine the two k-slab candidates (tie -> lower k) ---------
__global__ __launch_bounds__(256) void combine_kernel(const float* __restrict__ distc,
                                                      const int* __restrict__ idxc,
                                                      int* __restrict__ idx_out) {
  const int n = blockIdx.x * 256 + threadIdx.x;
  if (n >= NP) return;
  const float d0 = distc[n], d1 = distc[NP + n];
  idx_out[n] = (d1 < d0) ? idxc[NP + n] : idxc[n];   // tie keeps slab 0 (lower k)
}

// ---------------- residual in place: P^T[d][n] -= C1^T[d][idx1[n]] -----------
__global__ __launch_bounds__(256) void resid_kernel(float* __restrict__ PT,
                                                    const float* __restrict__ C1T,
                                                    const int* __restrict__ idx1) {
  const int d = blockIdx.y;
  const int n = blockIdx.x * 256 + threadIdx.x;
  const int k = idx1[n];
  PT[(size_t)d * NP + n] -= C1T[d * KC + k];
}

// ---------------- BN stats: per-channel sum & sumsq of LUT outputs -----------
__global__ __launch_bounds__(256) void stats_kernel(const int* __restrict__ idx1,
                                                    const int* __restrict__ idx2,
                                                    const float* __restrict__ dotc,
                                                    const float* __restrict__ dotrc,
                                                    float* __restrict__ gsum,
                                                    float* __restrict__ gsq) {
  __shared__ float ssum[4][128], ssq[4][128];
  const int tid = threadIdx.x, lane = tid & 63, wv = tid >> 6;
  const int wid = blockIdx.x * 4 + wv;           // 0..511
  float s0 = 0.f, s1 = 0.f, q0 = 0.f, q1 = 0.f;
  for (int n = wid; n < NP; n += 512) {          // 25088 = 512*49
    const int k1 = idx1[n], k2 = idx2[n];
    const float2 u = ((const float2*)(dotc + (size_t)k1 * 128))[lane];
    const float2 v = ((const float2*)(dotrc + (size_t)k2 * 128))[lane];
    const float x0 = u.x + v.x, x1 = u.y + v.y;
    s0 += x0; s1 += x1; q0 += x0 * x0; q1 += x1 * x1;
  }
  ssum[wv][lane * 2] = s0; ssum[wv][lane * 2 + 1] = s1;
  ssq[wv][lane * 2] = q0;  ssq[wv][lane * 2 + 1] = q1;
  __syncthreads();
  if (tid < 128) {
    const float s = ssum[0][tid] + ssum[1][tid] + ssum[2][tid] + ssum[3][tid];
    const float q = ssq[0][tid] + ssq[1][tid] + ssq[2][tid] + ssq[3][tid];
    atomicAdd(&gsum[tid], s);
    atomicAdd(&gsq[tid], q);
  }
}

__global__ void finalize_kernel(const float* __restrict__ gsum,
                                const float* __restrict__ gsq,
                                const float* __restrict__ gamma,
                                const float* __restrict__ beta,
                                float* __restrict__ scalev,
                                float* __restrict__ shiftv) {
  const int c = threadIdx.x;                     // 128
  const float mean = gsum[c] * (1.0f / NP);
  const float var = gsq[c] * (1.0f / NP) - mean * mean;
  const float inv = rsqrtf(var + 1e-5f);
  const float sc = gamma[c] * inv;
  scalev[c] = sc;
  shiftv[c] = beta[c] - mean * sc;
}

// ---------------- output: LUT gather + affine BN + [B,C,H,W] store -----------
__global__ __launch_bounds__(256) void output_kernel(const int* __restrict__ idx1,
                                                     const int* __restrict__ idx2,
                                                     const float* __restrict__ dotc,
                                                     const float* __restrict__ dotrc,
                                                     const float* __restrict__ scalev,
                                                     const float* __restrict__ shiftv,
                                                     float* __restrict__ out) {
  __shared__ float vals[64][128];                // [n-local][c]  32 KB
  const int tid = threadIdx.x, lane = tid & 63, wv = tid >> 6;
  const int blk = blockIdx.x;                    // 392 = 8 * 49
  const int b = blk / 49, hw0 = (blk % 49) * 64;
  const int n0 = b * 3136 + hw0;
  const float sc0 = scalev[lane * 2], sc1 = scalev[lane * 2 + 1];
  const float sh0 = shiftv[lane * 2], sh1 = shiftv[lane * 2 + 1];
  for (int t = 0; t < 16; ++t) {
    const int nn = wv * 16 + t;
    const int n = n0 + nn;
    const int k1 = idx1[n], k2 = idx2[n];
    const float2 u = ((const float2*)(dotc + (size_t)k1 * 128))[lane];
    const float2 v = ((const float2*)(dotrc + (size_t)k2 * 128))[lane];
    *(float2*)&vals[nn][lane * 2] =
        make_float2(sc0 * (u.x + v.x) + sh0, sc1 * (u.y + v.y) + sh1);
  }
  __syncthreads();
  const int c = tid >> 1, half = tid & 1;
  float* op = out + ((size_t)b * 128 + c) * 3136 + hw0 + half * 32;
#pragma unroll
  for (int i = 0; i < 32; i += 4) {
    float4 w4;
    w4.x = vals[half * 32 + i + 0][c];
    w4.y = vals[half * 32 + i + 1][c];
    w4.z = vals[half * 32 + i + 2][c];
    w4.w = vals[half * 32 + i + 3][c];
    *(float4*)(op + i) = w4;
  }
}

extern "C" void kernel_launch(void* const* d_in, const int* in_sizes, int n_in,
                              void* d_out, int out_size, void* d_ws, size_t ws_size,
                              hipStream_t stream) {
  const float* x     = (const float*)d_in[0];
  const float* cent  = (const float*)d_in[1];
  const float* rcent = (const float*)d_in[2];
  const float* dotc  = (const float*)d_in[3];
  const float* dotrc = (const float*)d_in[4];
  const float* gamma = (const float*)d_in[5];
  const float* beta  = (const float*)d_in[6];
  float* out = (float*)d_out;

  // workspace layout (~60 MB)
  float* PT  = (float*)d_ws;                 // [576][25088]
  float* C1T = PT + (size_t)DD * NP;         // [576][256]
  float* C2T = C1T + (size_t)DD * KC;        // [576][256]
  int* idx1  = (int*)(C2T + (size_t)DD * KC);
  int* idx2  = idx1 + NP;
  float* distc = (float*)(idx2 + NP);        // [2][25088]
  int* idxc    = (int*)(distc + 2 * NP);     // [2][25088]
  float* gsum   = (float*)(idxc + 2 * NP);   // [128]
  float* gsq    = gsum + 128;                // [128]
  float* scalev = gsq + 128;                 // [128]
  float* shiftv = scalev + 128;              // [128]

  unfold_kernel<<<dim3(98, 576), 256, 0, stream>>>(x, PT);
  transpose_kernel<<<576, 256, 0, stream>>>(cent, C1T);
  transpose_kernel<<<576, 256, 0, stream>>>(rcent, C2T);
  nearest_kernel<<<dim3(392, 2), 256, 0, stream>>>(PT, C1T, distc, idxc);
  combine_kernel<<<98, 256, 0, stream>>>(distc, idxc, idx1);
  resid_kernel<<<dim3(98, 576), 256, 0, stream>>>(PT, C1T, idx1);
  nearest_kernel<<<dim3(392, 2), 256, 0, stream>>>(PT, C2T, distc, idxc);
  combine_kernel<<<98, 256, 0, stream>>>(distc, idxc, idx2);
  hipMemsetAsync(gsum, 0, 256 * sizeof(float), stream);
  stats_kernel<<<128, 256, 0, stream>>>(idx1, idx2, dotc, dotrc, gsum, gsq);
  finalize_kernel<<<1, 128, 0, stream>>>(gsum, gsq, gamma, beta, scalev, shiftv);
  output_kernel<<<392, 256, 0, stream>>>(idx1, idx2, dotc, dotrc, scalev, shiftv, out);
}

// Round 3
// 737.042 us; speedup vs baseline: 1.0977x; 1.0121x over previous
//
#include <hip/hip_runtime.h>

#define NP 25088   // B * oH * oW = 8*56*56
#define DD 576     // 64 * 3 * 3
#define KC 256     // centroids

// ---------------- unfold: x[8,64,56,56] -> P^T[576][25088], d = c*9+i*3+j ----
__global__ __launch_bounds__(256) void unfold_kernel(const float* __restrict__ x,
                                                     float* __restrict__ PT) {
  const int d = blockIdx.y;                       // 0..575
  const int n = blockIdx.x * 256 + threadIdx.x;   // 0..25087
  const int c = d / 9, r = d % 9;
  const int di = r / 3 - 1, dj = r % 3 - 1;
  const int b = n / 3136, hw = n % 3136;
  const int h = hw / 56 + di, w = hw % 56 + dj;
  float v = 0.0f;
  if (h >= 0 && h < 56 && w >= 0 && w < 56)
    v = x[(((size_t)b * 64 + c) * 56 + h) * 56 + w];
  PT[(size_t)d * NP + n] = v;
}

// ---------------- centroid transpose: C[256][576] -> C^T[576][256] -----------
__global__ __launch_bounds__(256) void transpose_kernel(const float* __restrict__ C,
                                                        float* __restrict__ CT) {
  const int d = blockIdx.x;      // 576
  const int k = threadIdx.x;     // 256
  CT[d * KC + k] = C[k * DD + d];
}

// ---------------- nearest: per-block best over a 128-k slab ------------------
// block: 64 patches x 128 centroids (kc = blockIdx.y selects slab).
// grid (392, 2) = 784 blocks -> 3 blocks/CU resident (48 KB LDS).
// 256 threads, thread tile 4m x 8k. Dc=32 double-buffered LDS, split
// accumulation (64-d segments) for summation accuracy (argmin tie safety).
// __launch_bounds__(256, 3): LDS caps residency at 3 blocks/CU anyway; let
// the allocator use up to ~170 VGPRs so part/tot/staging never spill
// (R2 evidence: VGPR_Count=68 + 182 MB scratch write-back per dispatch).
__global__ __launch_bounds__(256, 3) void nearest_kernel(const float* __restrict__ AT,
                                                         const float* __restrict__ CT,
                                                         float* __restrict__ distc,
                                                         int* __restrict__ idxc) {
  __shared__ float As[2][32][64];    // [buf][d][m]   16 KB
  __shared__ float Bs[2][32][128];   // [buf][d][k]   32 KB

  const int tid = threadIdx.x;
  const int tm = tid >> 4;           // 0..15 -> m = tm*4 + i
  const int tk = tid & 15;           // 0..15 -> k = kc*128 + {tk*4+j, 64+tk*4+j}
  const int m0 = blockIdx.x * 64;
  const int kc = blockIdx.y;

  float part[4][8], tot[4][8];
  float4 ra[2], rb[4];

#define LOADT(ch) do {                                                              \
    _Pragma("unroll")                                                               \
    for (int q = 0; q < 2; ++q) {                                                   \
      int f = q * 256 + tid;                                                        \
      ra[q] = *(const float4*)(AT + (size_t)((ch) * 32 + (f >> 4)) * NP + m0 +      \
                               (f & 15) * 4);                                       \
    }                                                                               \
    _Pragma("unroll")                                                               \
    for (int q = 0; q < 4; ++q) {                                                   \
      int f = q * 256 + tid;                                                        \
      rb[q] = *(const float4*)(CT + (size_t)((ch) * 32 + (f >> 5)) * KC +           \
                               kc * 128 + (f & 31) * 4);                            \
    }                                                                               \
  } while (0)

#define WRITET(bf) do {                                                             \
    _Pragma("unroll")                                                               \
    for (int q = 0; q < 2; ++q) {                                                   \
      int f = q * 256 + tid;                                                        \
      *(float4*)&As[bf][f >> 4][(f & 15) * 4] = ra[q];                              \
    }                                                                               \
    _Pragma("unroll")                                                               \
    for (int q = 0; q < 4; ++q) {                                                   \
      int f = q * 256 + tid;                                                        \
      *(float4*)&Bs[bf][f >> 5][(f & 31) * 4] = rb[q];                              \
    }                                                                               \
  } while (0)

  LOADT(0);
  WRITET(0);
#pragma unroll
  for (int i = 0; i < 4; ++i)
#pragma unroll
    for (int j = 0; j < 8; ++j) tot[i][j] = 0.0f;

  for (int ch = 0; ch < 18; ++ch) {            // 18 * 32 = 576 d's
    if ((ch & 1) == 0) {
#pragma unroll
      for (int i = 0; i < 4; ++i)
#pragma unroll
        for (int j = 0; j < 8; ++j) part[i][j] = 0.0f;
    }
    __syncthreads();                           // staged buf (ch&1) visible
    if (ch < 17) LOADT(ch + 1);                // issue next-chunk global loads
    const int buf = ch & 1;
#pragma unroll 4
    for (int d = 0; d < 32; ++d) {
      float a[4], b[8];
      *(float4*)&a[0] = *(const float4*)&As[buf][d][tm * 4];
      *(float4*)&b[0] = *(const float4*)&Bs[buf][d][tk * 4];
      *(float4*)&b[4] = *(const float4*)&Bs[buf][d][64 + tk * 4];
#pragma unroll
      for (int i = 0; i < 4; ++i)
#pragma unroll
        for (int j = 0; j < 8; ++j) part[i][j] += fabsf(a[i] - b[j]);
    }
    if (ch < 17) WRITET((ch + 1) & 1);         // ds_write after compute (T14)
    if (ch & 1) {                              // segment flush (64 d's)
#pragma unroll
      for (int i = 0; i < 4; ++i)
#pragma unroll
        for (int j = 0; j < 8; ++j) tot[i][j] += part[i][j];
    }
  }

  // per-thread argmin over its 8 k's (ascending k, strict < => first-min),
  // then butterfly reduce across the 16 tk lanes sharing this m-row.
#pragma unroll
  for (int i = 0; i < 4; ++i) {
    float bd = tot[i][0];
    int bk = kc * 128 + tk * 4;
#pragma unroll
    for (int j = 1; j < 8; ++j) {
      int kk = kc * 128 + (j < 4 ? tk * 4 + j : 64 + tk * 4 + (j - 4));
      if (tot[i][j] < bd) { bd = tot[i][j]; bk = kk; }
    }
#pragma unroll
    for (int off = 1; off < 16; off <<= 1) {
      float od = __shfl_xor(bd, off, 64);
      int ok = __shfl_xor(bk, off, 64);
      if (od < bd || (od == bd && ok < bk)) { bd = od; bk = ok; }
    }
    if (tk == 0) {
      const int m = m0 + tm * 4 + i;
      distc[(size_t)kc * NP + m] = bd;
      idxc[(size_t)kc * NP + m] = bk;
    }
  }
#undef LOADT
#undef WRITET
}

// ---------------- combine the two k-slab candidates (tie -> lower k) ---------
__global__ __launch_bounds__(256) void combine_kernel(const float* __restrict__ distc,
                                                      const int* __restrict__ idxc,
                                                      int* __restrict__ idx_out) {
  const int n = blockIdx.x * 256 + threadIdx.x;
  if (n >= NP) return;
  const float d0 = distc[n], d1 = distc[NP + n];
  idx_out[n] = (d1 < d0) ? idxc[NP + n] : idxc[n];   // tie keeps slab 0 (lower k)
}

// ---------------- residual in place: P^T[d][n] -= C1^T[d][idx1[n]] -----------
__global__ __launch_bounds__(256) void resid_kernel(float* __restrict__ PT,
                                                    const float* __restrict__ C1T,
                                                    const int* __restrict__ idx1) {
  const int d = blockIdx.y;
  const int n = blockIdx.x * 256 + threadIdx.x;
  const int k = idx1[n];
  PT[(size_t)d * NP + n] -= C1T[d * KC + k];
}

// ---------------- BN stats: per-channel sum & sumsq of LUT outputs -----------
__global__ __launch_bounds__(256) void stats_kernel(const int* __restrict__ idx1,
                                                    const int* __restrict__ idx2,
                                                    const float* __restrict__ dotc,
                                                    const float* __restrict__ dotrc,
                                                    float* __restrict__ gsum,
                                                    float* __restrict__ gsq) {
  __shared__ float ssum[4][128], ssq[4][128];
  const int tid = threadIdx.x, lane = tid & 63, wv = tid >> 6;
  const int wid = blockIdx.x * 4 + wv;           // 0..511
  float s0 = 0.f, s1 = 0.f, q0 = 0.f, q1 = 0.f;
  for (int n = wid; n < NP; n += 512) {          // 25088 = 512*49
    const int k1 = idx1[n], k2 = idx2[n];
    const float2 u = ((const float2*)(dotc + (size_t)k1 * 128))[lane];
    const float2 v = ((const float2*)(dotrc + (size_t)k2 * 128))[lane];
    const float x0 = u.x + v.x, x1 = u.y + v.y;
    s0 += x0; s1 += x1; q0 += x0 * x0; q1 += x1 * x1;
  }
  ssum[wv][lane * 2] = s0; ssum[wv][lane * 2 + 1] = s1;
  ssq[wv][lane * 2] = q0;  ssq[wv][lane * 2 + 1] = q1;
  __syncthreads();
  if (tid < 128) {
    const float s = ssum[0][tid] + ssum[1][tid] + ssum[2][tid] + ssum[3][tid];
    const float q = ssq[0][tid] + ssq[1][tid] + ssq[2][tid] + ssq[3][tid];
    atomicAdd(&gsum[tid], s);
    atomicAdd(&gsq[tid], q);
  }
}

__global__ void finalize_kernel(const float* __restrict__ gsum,
                                const float* __restrict__ gsq,
                                const float* __restrict__ gamma,
                                const float* __restrict__ beta,
                                float* __restrict__ scalev,
                                float* __restrict__ shiftv) {
  const int c = threadIdx.x;                     // 128
  const float mean = gsum[c] * (1.0f / NP);
  const float var = gsq[c] * (1.0f / NP) - mean * mean;
  const float inv = rsqrtf(var + 1e-5f);
  const float sc = gamma[c] * inv;
  scalev[c] = sc;
  shiftv[c] = beta[c] - mean * sc;
}

// ---------------- output: LUT gather + affine BN + [B,C,H,W] store -----------
__global__ __launch_bounds__(256) void output_kernel(const int* __restrict__ idx1,
                                                     const int* __restrict__ idx2,
                                                     const float* __restrict__ dotc,
                                                     const float* __restrict__ dotrc,
                                                     const float* __restrict__ scalev,
                                                     const float* __restrict__ shiftv,
                                                     float* __restrict__ out) {
  __shared__ float vals[64][128];                // [n-local][c]  32 KB
  const int tid = threadIdx.x, lane = tid & 63, wv = tid >> 6;
  const int blk = blockIdx.x;                    // 392 = 8 * 49
  const int b = blk / 49, hw0 = (blk % 49) * 64;
  const int n0 = b * 3136 + hw0;
  const float sc0 = scalev[lane * 2], sc1 = scalev[lane * 2 + 1];
  const float sh0 = shiftv[lane * 2], sh1 = shiftv[lane * 2 + 1];
  for (int t = 0; t < 16; ++t) {
    const int nn = wv * 16 + t;
    const int n = n0 + nn;
    const int k1 = idx1[n], k2 = idx2[n];
    const float2 u = ((const float2*)(dotc + (size_t)k1 * 128))[lane];
    const float2 v = ((const float2*)(dotrc + (size_t)k2 * 128))[lane];
    *(float2*)&vals[nn][lane * 2] =
        make_float2(sc0 * (u.x + v.x) + sh0, sc1 * (u.y + v.y) + sh1);
  }
  __syncthreads();
  const int c = tid >> 1, half = tid & 1;
  float* op = out + ((size_t)b * 128 + c) * 3136 + hw0 + half * 32;
#pragma unroll
  for (int i = 0; i < 32; i += 4) {
    float4 w4;
    w4.x = vals[half * 32 + i + 0][c];
    w4.y = vals[half * 32 + i + 1][c];
    w4.z = vals[half * 32 + i + 2][c];
    w4.w = vals[half * 32 + i + 3][c];
    *(float4*)(op + i) = w4;
  }
}

extern "C" void kernel_launch(void* const* d_in, const int* in_sizes, int n_in,
                              void* d_out, int out_size, void* d_ws, size_t ws_size,
                              hipStream_t stream) {
  const float* x     = (const float*)d_in[0];
  const float* cent  = (const float*)d_in[1];
  const float* rcent = (const float*)d_in[2];
  const float* dotc  = (const float*)d_in[3];
  const float* dotrc = (const float*)d_in[4];
  const float* gamma = (const float*)d_in[5];
  const float* beta  = (const float*)d_in[6];
  float* out = (float*)d_out;

  // workspace layout (~60 MB)
  float* PT  = (float*)d_ws;                 // [576][25088]
  float* C1T = PT + (size_t)DD * NP;         // [576][256]
  float* C2T = C1T + (size_t)DD * KC;        // [576][256]
  int* idx1  = (int*)(C2T + (size_t)DD * KC);
  int* idx2  = idx1 + NP;
  float* distc = (float*)(idx2 + NP);        // [2][25088]
  int* idxc    = (int*)(distc + 2 * NP);     // [2][25088]
  float* gsum   = (float*)(idxc + 2 * NP);   // [128]
  float* gsq    = gsum + 128;                // [128]
  float* scalev = gsq + 128;                 // [128]
  float* shiftv = scalev + 128;              // [128]

  unfold_kernel<<<dim3(98, 576), 256, 0, stream>>>(x, PT);
  transpose_kernel<<<576, 256, 0, stream>>>(cent, C1T);
  transpose_kernel<<<576, 256, 0, stream>>>(rcent, C2T);
  nearest_kernel<<<dim3(392, 2), 256, 0, stream>>>(PT, C1T, distc, idxc);
  combine_kernel<<<98, 256, 0, stream>>>(distc, idxc, idx1);
  resid_kernel<<<dim3(98, 576), 256, 0, stream>>>(PT, C1T, idx1);
  nearest_kernel<<<dim3(392, 2), 256, 0, stream>>>(PT, C2T, distc, idxc);
  combine_kernel<<<98, 256, 0, stream>>>(distc, idxc, idx2);
  hipMemsetAsync(gsum, 0, 256 * sizeof(float), stream);
  stats_kernel<<<128, 256, 0, stream>>>(idx1, idx2, dotc, dotrc, gsum, gsq);
  finalize_kernel<<<1, 128, 0, stream>>>(gsum, gsq, gamma, beta, scalev, shiftv);
  output_kernel<<<392, 256, 0, stream>>>(idx1, idx2, dotc, dotrc, scalev, shiftv, out);
}

// Round 4
// 589.749 us; speedup vs baseline: 1.3718x; 1.2498x over previous
//
#include <hip/hip_runtime.h>

#define NP 25088   // B * oH * oW = 8*56*56
#define DD 576     // 64 * 3 * 3
#define KC 256     // centroids

// ---------------- unfold: x[8,64,56,56] -> P^T[576][25088], d = c*9+i*3+j ----
__global__ __launch_bounds__(256) void unfold_kernel(const float* __restrict__ x,
                                                     float* __restrict__ PT) {
  const int d = blockIdx.y;                       // 0..575
  const int n = blockIdx.x * 256 + threadIdx.x;   // 0..25087
  const int c = d / 9, r = d % 9;
  const int di = r / 3 - 1, dj = r % 3 - 1;
  const int b = n / 3136, hw = n % 3136;
  const int h = hw / 56 + di, w = hw % 56 + dj;
  float v = 0.0f;
  if (h >= 0 && h < 56 && w >= 0 && w < 56)
    v = x[(((size_t)b * 64 + c) * 56 + h) * 56 + w];
  PT[(size_t)d * NP + n] = v;
}

// ---------------- centroid transpose: C[256][576] -> C^T[576][256] -----------
__global__ __launch_bounds__(256) void transpose_kernel(const float* __restrict__ C,
                                                        float* __restrict__ CT) {
  const int d = blockIdx.x;      // 576
  const int k = threadIdx.x;     // 256
  CT[d * KC + k] = C[k * DD + d];
}

// ---------------- nearest: per-block best over a 64-k slab -------------------
// block: 64 patches x 64 centroids. 1568 blocks (392 m-groups x 4 k-slabs),
// XCD-chunk swizzled so one m-group's 4 slabs share an XCD L2.
// LDS 32 KB -> 5 blocks/CU (160 KB), 20 waves/CU.
// 256 threads, thread tile 4m x 4k. ALL per-thread state is named float4
// scalars (R3 evidence: array locals stayed in scratch -> 180 MB WRITE_SIZE).
// part/tot split accumulation (64-d segments) for argmin tie accuracy.
#define ACC4(p, a, s) \
  do { p.x += fabsf(a.x - (s)); p.y += fabsf(a.y - (s)); \
       p.z += fabsf(a.z - (s)); p.w += fabsf(a.w - (s)); } while (0)
#define ADD4(t, p) \
  do { t.x += p.x; t.y += p.y; t.z += p.z; t.w += p.w; } while (0)
#define COMP(v, i) ((i) == 0 ? (v).x : (i) == 1 ? (v).y : (i) == 2 ? (v).z : (v).w)

__global__ __launch_bounds__(256, 5) void nearest_kernel(const float* __restrict__ AT,
                                                         const float* __restrict__ CT,
                                                         float* __restrict__ distc,
                                                         int* __restrict__ idxc) {
  __shared__ float As[2][32][64];    // [buf][d][m]   16 KB
  __shared__ float Bs[2][32][64];    // [buf][d][k]   16 KB

  const int tid = threadIdx.x;
  const int tm = tid >> 4;           // 0..15 -> m = m0 + tm*4 + i
  const int tk = tid & 15;           // 0..15 -> k = k0 + tk*4 + j
  // XCD-chunk swizzle: hardware round-robins linear blockIdx across 8 XCDs;
  // give XCD x the m-groups [49x, 49x+49), all 4 k-slabs back-to-back.
  const int L = blockIdx.x;          // 0..1567 (= 8 * 196)
  const int xcd = L & 7, r = L >> 3;
  const int mb = xcd * 49 + (r >> 2);    // 0..391
  const int kc = r & 3;                  // 0..3
  const int m0 = mb * 64, k0 = kc * 64;

  // staging + accumulators: named float4 only (no local arrays anywhere)
  float4 ra0, ra1, rb0, rb1;
  float4 p0, p1, p2, p3, t0, t1, t2, t3;

  const int frow = tid >> 4, fcol = (tid & 15) * 4;
  const float* ap = AT + (size_t)frow * NP + m0 + fcol;   // rows frow, frow+16
  const float* bp = CT + frow * KC + k0 + fcol;

#define LOADT() do {                                       \
    ra0 = *(const float4*)(ap);                            \
    ra1 = *(const float4*)(ap + (size_t)16 * NP);          \
    rb0 = *(const float4*)(bp);                            \
    rb1 = *(const float4*)(bp + 16 * KC);                  \
    ap += (size_t)32 * NP; bp += 32 * KC;                  \
  } while (0)

#define WRITET(bf) do {                                    \
    *(float4*)&As[bf][frow][fcol] = ra0;                   \
    *(float4*)&As[bf][16 + frow][fcol] = ra1;              \
    *(float4*)&Bs[bf][frow][fcol] = rb0;                   \
    *(float4*)&Bs[bf][16 + frow][fcol] = rb1;              \
  } while (0)

  LOADT();
  WRITET(0);
  t0 = t1 = t2 = t3 = make_float4(0.f, 0.f, 0.f, 0.f);

  for (int ch = 0; ch < 18; ++ch) {            // 18 * 32 = 576 d's
    if ((ch & 1) == 0) p0 = p1 = p2 = p3 = make_float4(0.f, 0.f, 0.f, 0.f);
    __syncthreads();                           // staged buf (ch&1) visible
    if (ch < 17) LOADT();                      // issue next-chunk global loads
    const int buf = ch & 1;
#pragma unroll 8
    for (int d = 0; d < 32; ++d) {
      const float4 a = *(const float4*)&As[buf][d][tm * 4];
      const float4 b = *(const float4*)&Bs[buf][d][tk * 4];
      ACC4(p0, a, b.x);
      ACC4(p1, a, b.y);
      ACC4(p2, a, b.z);
      ACC4(p3, a, b.w);
    }
    if (ch < 17) WRITET((ch + 1) & 1);         // ds_write after compute (T14)
    if (ch & 1) {                              // segment flush (64 d's)
      ADD4(t0, p0); ADD4(t1, p1); ADD4(t2, p2); ADD4(t3, p3);
    }
  }

  // per-thread argmin over its 4 k's (ascending, strict < => first-min),
  // then butterfly reduce across the 16 tk lanes sharing this m-row.
#pragma unroll
  for (int i = 0; i < 4; ++i) {
    const float d0 = COMP(t0, i), d1 = COMP(t1, i), d2 = COMP(t2, i), d3 = COMP(t3, i);
    float bd = d0;
    int bk = k0 + tk * 4;
    if (d1 < bd) { bd = d1; bk = k0 + tk * 4 + 1; }
    if (d2 < bd) { bd = d2; bk = k0 + tk * 4 + 2; }
    if (d3 < bd) { bd = d3; bk = k0 + tk * 4 + 3; }
#pragma unroll
    for (int off = 1; off < 16; off <<= 1) {
      const float od = __shfl_xor(bd, off, 64);
      const int ok = __shfl_xor(bk, off, 64);
      if (od < bd || (od == bd && ok < bk)) { bd = od; bk = ok; }
    }
    if (tk == 0) {
      const int m = m0 + tm * 4 + i;
      distc[(size_t)kc * NP + m] = bd;
      idxc[(size_t)kc * NP + m] = bk;
    }
  }
#undef LOADT
#undef WRITET
}

// ---------------- combine the four k-slab candidates (tie -> lower k) --------
__global__ __launch_bounds__(256) void combine_kernel(const float* __restrict__ distc,
                                                      const int* __restrict__ idxc,
                                                      int* __restrict__ idx_out) {
  const int n = blockIdx.x * 256 + threadIdx.x;
  if (n >= NP) return;
  float bd = distc[n];
  int bi = idxc[n];
#pragma unroll
  for (int s = 1; s < 4; ++s) {
    const float d = distc[(size_t)s * NP + n];
    if (d < bd) { bd = d; bi = idxc[(size_t)s * NP + n]; }  // tie keeps lower slab
  }
  idx_out[n] = bi;
}

// ---------------- residual in place: P^T[d][n] -= C1^T[d][idx1[n]] -----------
__global__ __launch_bounds__(256) void resid_kernel(float* __restrict__ PT,
                                                    const float* __restrict__ C1T,
                                                    const int* __restrict__ idx1) {
  const int d = blockIdx.y;
  const int n = blockIdx.x * 256 + threadIdx.x;
  const int k = idx1[n];
  PT[(size_t)d * NP + n] -= C1T[d * KC + k];
}

// ---------------- BN stats: per-channel sum & sumsq of LUT outputs -----------
__global__ __launch_bounds__(256) void stats_kernel(const int* __restrict__ idx1,
                                                    const int* __restrict__ idx2,
                                                    const float* __restrict__ dotc,
                                                    const float* __restrict__ dotrc,
                                                    float* __restrict__ gsum,
                                                    float* __restrict__ gsq) {
  __shared__ float ssum[4][128], ssq[4][128];
  const int tid = threadIdx.x, lane = tid & 63, wv = tid >> 6;
  const int wid = blockIdx.x * 4 + wv;           // 0..511
  float s0 = 0.f, s1 = 0.f, q0 = 0.f, q1 = 0.f;
  for (int n = wid; n < NP; n += 512) {          // 25088 = 512*49
    const int k1 = idx1[n], k2 = idx2[n];
    const float2 u = ((const float2*)(dotc + (size_t)k1 * 128))[lane];
    const float2 v = ((const float2*)(dotrc + (size_t)k2 * 128))[lane];
    const float x0 = u.x + v.x, x1 = u.y + v.y;
    s0 += x0; s1 += x1; q0 += x0 * x0; q1 += x1 * x1;
  }
  ssum[wv][lane * 2] = s0; ssum[wv][lane * 2 + 1] = s1;
  ssq[wv][lane * 2] = q0;  ssq[wv][lane * 2 + 1] = q1;
  __syncthreads();
  if (tid < 128) {
    const float s = ssum[0][tid] + ssum[1][tid] + ssum[2][tid] + ssum[3][tid];
    const float q = ssq[0][tid] + ssq[1][tid] + ssq[2][tid] + ssq[3][tid];
    atomicAdd(&gsum[tid], s);
    atomicAdd(&gsq[tid], q);
  }
}

__global__ void finalize_kernel(const float* __restrict__ gsum,
                                const float* __restrict__ gsq,
                                const float* __restrict__ gamma,
                                const float* __restrict__ beta,
                                float* __restrict__ scalev,
                                float* __restrict__ shiftv) {
  const int c = threadIdx.x;                     // 128
  const float mean = gsum[c] * (1.0f / NP);
  const float var = gsq[c] * (1.0f / NP) - mean * mean;
  const float inv = rsqrtf(var + 1e-5f);
  const float sc = gamma[c] * inv;
  scalev[c] = sc;
  shiftv[c] = beta[c] - mean * sc;
}

// ---------------- output: LUT gather + affine BN + [B,C,H,W] store -----------
__global__ __launch_bounds__(256) void output_kernel(const int* __restrict__ idx1,
                                                     const int* __restrict__ idx2,
                                                     const float* __restrict__ dotc,
                                                     const float* __restrict__ dotrc,
                                                     const float* __restrict__ scalev,
                                                     const float* __restrict__ shiftv,
                                                     float* __restrict__ out) {
  __shared__ float vals[64][128];                // [n-local][c]  32 KB
  const int tid = threadIdx.x, lane = tid & 63, wv = tid >> 6;
  const int blk = blockIdx.x;                    // 392 = 8 * 49
  const int b = blk / 49, hw0 = (blk % 49) * 64;
  const int n0 = b * 3136 + hw0;
  const float sc0 = scalev[lane * 2], sc1 = scalev[lane * 2 + 1];
  const float sh0 = shiftv[lane * 2], sh1 = shiftv[lane * 2 + 1];
  for (int t = 0; t < 16; ++t) {
    const int nn = wv * 16 + t;
    const int n = n0 + nn;
    const int k1 = idx1[n], k2 = idx2[n];
    const float2 u = ((const float2*)(dotc + (size_t)k1 * 128))[lane];
    const float2 v = ((const float2*)(dotrc + (size_t)k2 * 128))[lane];
    *(float2*)&vals[nn][lane * 2] =
        make_float2(sc0 * (u.x + v.x) + sh0, sc1 * (u.y + v.y) + sh1);
  }
  __syncthreads();
  const int c = tid >> 1, half = tid & 1;
  float* op = out + ((size_t)b * 128 + c) * 3136 + hw0 + half * 32;
#pragma unroll
  for (int i = 0; i < 32; i += 4) {
    float4 w4;
    w4.x = vals[half * 32 + i + 0][c];
    w4.y = vals[half * 32 + i + 1][c];
    w4.z = vals[half * 32 + i + 2][c];
    w4.w = vals[half * 32 + i + 3][c];
    *(float4*)(op + i) = w4;
  }
}

extern "C" void kernel_launch(void* const* d_in, const int* in_sizes, int n_in,
                              void* d_out, int out_size, void* d_ws, size_t ws_size,
                              hipStream_t stream) {
  const float* x     = (const float*)d_in[0];
  const float* cent  = (const float*)d_in[1];
  const float* rcent = (const float*)d_in[2];
  const float* dotc  = (const float*)d_in[3];
  const float* dotrc = (const float*)d_in[4];
  const float* gamma = (const float*)d_in[5];
  const float* beta  = (const float*)d_in[6];
  float* out = (float*)d_out;

  // workspace layout (~60 MB)
  float* PT  = (float*)d_ws;                 // [576][25088]
  float* C1T = PT + (size_t)DD * NP;         // [576][256]
  float* C2T = C1T + (size_t)DD * KC;        // [576][256]
  int* idx1  = (int*)(C2T + (size_t)DD * KC);
  int* idx2  = idx1 + NP;
  float* distc = (float*)(idx2 + NP);        // [4][25088]
  int* idxc    = (int*)(distc + 4 * NP);     // [4][25088]
  float* gsum   = (float*)(idxc + 4 * NP);   // [128]
  float* gsq    = gsum + 128;                // [128]
  float* scalev = gsq + 128;                 // [128]
  float* shiftv = scalev + 128;              // [128]

  unfold_kernel<<<dim3(98, 576), 256, 0, stream>>>(x, PT);
  transpose_kernel<<<576, 256, 0, stream>>>(cent, C1T);
  transpose_kernel<<<576, 256, 0, stream>>>(rcent, C2T);
  nearest_kernel<<<1568, 256, 0, stream>>>(PT, C1T, distc, idxc);
  combine_kernel<<<98, 256, 0, stream>>>(distc, idxc, idx1);
  resid_kernel<<<dim3(98, 576), 256, 0, stream>>>(PT, C1T, idx1);
  nearest_kernel<<<1568, 256, 0, stream>>>(PT, C2T, distc, idxc);
  combine_kernel<<<98, 256, 0, stream>>>(distc, idxc, idx2);
  hipMemsetAsync(gsum, 0, 256 * sizeof(float), stream);
  stats_kernel<<<128, 256, 0, stream>>>(idx1, idx2, dotc, dotrc, gsum, gsq);
  finalize_kernel<<<1, 128, 0, stream>>>(gsum, gsq, gamma, beta, scalev, shiftv);
  output_kernel<<<392, 256, 0, stream>>>(idx1, idx2, dotc, dotrc, scalev, shiftv, out);
}